// Round 7
// baseline (129.408 us; speedup 1.0000x reference)
//
#include <hip/hip_runtime.h>
#include <cstddef>

#define BB 16
#define PP 4
#define HH 32
#define WW 32
#define DD 32
#define CC 8
#define TT 16   // h-tiles per block

typedef float fx4 __attribute__((ext_vector_type(4)));

// Pipelined tile loop: each block owns a 16h x 4w x 32d slab; per iteration a
// thread handles one voxel-half (8 corner loads). Loads for tile t+1 are issued
// BEFORE consuming tile t -> steady-state vmcnt(8) in flight per wave, first-load
// latency paid once per block instead of once per wave (R6 post-mortem).
// sched_barrier(0) fences pin the pipeline (R5: compiler re-serializes otherwise).
// Branch-free gather: clamped addresses, zeroed weights for out-of-volume corners.
__global__ __launch_bounds__(256) void resample_kernel(
    const float* __restrict__ fmap,
    const float* __restrict__ theta,
    float* __restrict__ out)
{
    const int bp  = blockIdx.x >> 4;          // 16 blocks per (b,p)
    const int hb  = (blockIdx.x >> 3) & 1;    // 2 h-slabs of 16
    const int wb  = blockIdx.x & 7;           // 8 w-quads
    const int tid  = threadIdx.x;
    const int half = tid & 1;                 // which float4 of the 8 channels
    const int d    = (tid >> 1) & 31;
    const int w    = (wb << 2) + (tid >> 6);  // one w per wave
    const int hbase = hb << 4;

    const float* th = theta + bp * 12;
    const float t1 = th[1], t5 = th[5], t9 = th[9];
    const float fw = (float)w, fd = (float)d;
    // h-invariant part of the affine (meshgrid 'xy': x<-w, y<-h, z<-d; +2 pad)
    const float xw = fmaf(th[0], fw, fmaf(th[2],  fd, th[3] )) + 2.0f;
    const float yw = fmaf(th[4], fw, fmaf(th[6],  fd, th[7] )) + 2.0f;
    const float zw = fmaf(th[8], fw, fmaf(th[10], fd, th[11])) + 2.0f;

    const float* __restrict__ base = fmap + (size_t)bp * (HH * WW * DD * CC) + half * 4;
    float* __restrict__ obase = out + (size_t)bp * (HH * WW * DD * CC)
                                + (size_t)((hbase * WW + w) * DD + d) * CC + half * 4;

    auto calc = [&](int t, unsigned off[8], float wgt[8]) {
        const float fh = (float)(hbase + t);
        const float x = fmaf(t1, fh, xw);
        const float y = fmaf(t5, fh, yw);
        const float z = fmaf(t9, fh, zw);
        // faithful: floor -> clip to [0, H+2] in padded coords (all axes H+2)
        const int x0 = min(max((int)floorf(x), 0), HH + 2);
        const int y0 = min(max((int)floorf(y), 0), HH + 2);
        const int z0 = min(max((int)floorf(z), 0), HH + 2);
        const float xd = x - (float)x0, yd = y - (float)y0, zd = z - (float)z0;
        const int ix[2] = { x0 - 2, x0 - 1 };   // x indexes the H axis (ref quirk)
        const int iy[2] = { y0 - 2, y0 - 1 };
        const int iz[2] = { z0 - 2, z0 - 1 };
        const float wxv[2] = { (1.0f - xd) * (((unsigned)ix[0] < (unsigned)HH) ? 1.0f : 0.0f),
                               xd          * (((unsigned)ix[1] < (unsigned)HH) ? 1.0f : 0.0f) };
        const float wyv[2] = { (1.0f - yd) * (((unsigned)iy[0] < (unsigned)WW) ? 1.0f : 0.0f),
                               yd          * (((unsigned)iy[1] < (unsigned)WW) ? 1.0f : 0.0f) };
        const float wzv[2] = { (1.0f - zd) * (((unsigned)iz[0] < (unsigned)DD) ? 1.0f : 0.0f),
                               zd          * (((unsigned)iz[1] < (unsigned)DD) ? 1.0f : 0.0f) };
        const unsigned ox[2] = { (unsigned)(min(max(ix[0], 0), HH - 1) * (WW * DD * CC)),
                                 (unsigned)(min(max(ix[1], 0), HH - 1) * (WW * DD * CC)) };
        const unsigned oy[2] = { (unsigned)(min(max(iy[0], 0), WW - 1) * (DD * CC)),
                                 (unsigned)(min(max(iy[1], 0), WW - 1) * (DD * CC)) };
        const unsigned oz[2] = { (unsigned)(min(max(iz[0], 0), DD - 1) * CC),
                                 (unsigned)(min(max(iz[1], 0), DD - 1) * CC) };
        #pragma unroll
        for (int i = 0; i < 8; ++i) {
            const int bx = (i >> 2) & 1, by = (i >> 1) & 1, bz = i & 1;
            off[i] = ox[bx] + oy[by] + oz[bz];
            wgt[i] = wxv[bx] * wyv[by] * wzv[bz];
        }
    };
    auto loadv = [&](const unsigned off[8], fx4 c[8]) {
        #pragma unroll
        for (int i = 0; i < 8; ++i)
            c[i] = *(const fx4*)(base + off[i]);
    };
    auto consume = [&](int t, const fx4 c[8], const float wgt[8]) {
        fx4 acc = (fx4){0.f, 0.f, 0.f, 0.f};
        #pragma unroll
        for (int i = 0; i < 8; ++i) {
            acc.x = fmaf(wgt[i], c[i].x, acc.x);
            acc.y = fmaf(wgt[i], c[i].y, acc.y);
            acc.z = fmaf(wgt[i], c[i].z, acc.z);
            acc.w = fmaf(wgt[i], c[i].w, acc.w);
        }
        __builtin_nontemporal_store(acc, (fx4*)(obase + t * (WW * DD * CC)));
    };

    unsigned offA[8], offB[8];
    float    wgtA[8], wgtB[8];
    fx4      cA[8],   cB[8];

    calc(0, offA, wgtA);
    loadv(offA, cA);

    #pragma unroll
    for (int t = 0; t < TT; ++t) {
        const bool even = (t & 1) == 0;
        if (t + 1 < TT) {
            // issue next tile's 8 loads first -> consume below waits vmcnt(8)
            calc(t + 1, even ? offB : offA, even ? wgtB : wgtA);
            loadv(even ? offB : offA, even ? cB : cA);
        }
        __builtin_amdgcn_sched_barrier(0);
        consume(t, even ? cA : cB, even ? wgtA : wgtB);
        __builtin_amdgcn_sched_barrier(0);
    }
}

extern "C" void kernel_launch(void* const* d_in, const int* in_sizes, int n_in,
                              void* d_out, int out_size, void* d_ws, size_t ws_size,
                              hipStream_t stream) {
    const float* fmap  = (const float*)d_in[0];
    const float* theta = (const float*)d_in[1];
    float* out = (float*)d_out;

    const int total_blocks = BB * PP * 16;   // 1024 blocks, 16h x 4w x 32d slab each
    resample_kernel<<<dim3(total_blocks), dim3(256), 0, stream>>>(fmap, theta, out);
}

// Round 8
// 121.166 us; speedup vs baseline: 1.0680x; 1.0680x over previous
//
#include <hip/hip_runtime.h>
#include <cstddef>

#define BB 16
#define PP 4
#define HH 32
#define WW 32
#define DD 32
#define CC 8

typedef float fx4 __attribute__((ext_vector_type(4)));

// Two voxels per thread (h0, h0+1). The 16 corner loads are issued as inline-asm
// global_load_dwordx4 (volatile => pinned order, 64 live dest VGPRs => the
// register allocator CANNOT re-serialize them, unlike R5/R7 where it collapsed
// the pipeline to VGPR=48). Explicit s_waitcnt asm: vmcnt(8) -> consume voxel 0
// while voxel 1's loads are still in flight, vmcnt(0) -> consume voxel 1.
// sched_barrier(0) fences stop FMA uses from being hoisted past the waitcnts.
// Branch-free gather: clamped addresses, zeroed weights for OOV corners.
__global__ __launch_bounds__(256) void resample_kernel(
    const float* __restrict__ fmap,
    const float* __restrict__ theta,
    float* __restrict__ out)
{
    const int bp   = blockIdx.x >> 7;            // 128 blocks per (b,p)
    const int idx  = blockIdx.x & 127;
    const int h0   = (idx >> 3) << 1;            // 16 h-pairs
    const int w0   = (idx & 7) << 2;             // 8 w-quads
    const int tid  = threadIdx.x;
    const int half = tid & 1;                    // which float4 of the 8 channels
    const int d    = (tid >> 1) & 31;
    const int w    = w0 + (tid >> 6);            // one w per wave

    const float* th = theta + bp * 12;
    const float t0 = th[0], t1 = th[1], t2 = th[2],  t3  = th[3];
    const float t4 = th[4], t5 = th[5], t6 = th[6],  t7  = th[7];
    const float t8 = th[8], t9 = th[9], t10 = th[10], t11 = th[11];

    const float fw = (float)w, fd = (float)d;
    const float* __restrict__ base = fmap + (size_t)bp * (HH * WW * DD * CC) + half * 4;

    unsigned off[2][8];
    float    wgt[2][8];

    #pragma unroll
    for (int v = 0; v < 2; ++v) {
        const float fh = (float)(h0 + v);
        // meshgrid 'xy': grid point is (x=w, y=h, z=d); +2 pad offset
        const float x = fmaf(t0, fw, fmaf(t1, fh, fmaf(t2,  fd, t3 ))) + 2.0f;
        const float y = fmaf(t4, fw, fmaf(t5, fh, fmaf(t6,  fd, t7 ))) + 2.0f;
        const float z = fmaf(t8, fw, fmaf(t9, fh, fmaf(t10, fd, t11))) + 2.0f;

        // faithful: floor -> clip to [0, H+2] in padded coords (all axes H+2)
        const int x0 = min(max((int)floorf(x), 0), HH + 2);
        const int y0 = min(max((int)floorf(y), 0), HH + 2);
        const int z0 = min(max((int)floorf(z), 0), HH + 2);
        const float xd = x - (float)x0, yd = y - (float)y0, zd = z - (float)z0;

        const int ix[2] = { x0 - 2, x0 - 1 };    // x indexes the H axis (ref quirk)
        const int iy[2] = { y0 - 2, y0 - 1 };
        const int iz[2] = { z0 - 2, z0 - 1 };
        const float wxv[2] = { (1.0f - xd) * (((unsigned)ix[0] < (unsigned)HH) ? 1.0f : 0.0f),
                               xd          * (((unsigned)ix[1] < (unsigned)HH) ? 1.0f : 0.0f) };
        const float wyv[2] = { (1.0f - yd) * (((unsigned)iy[0] < (unsigned)WW) ? 1.0f : 0.0f),
                               yd          * (((unsigned)iy[1] < (unsigned)WW) ? 1.0f : 0.0f) };
        const float wzv[2] = { (1.0f - zd) * (((unsigned)iz[0] < (unsigned)DD) ? 1.0f : 0.0f),
                               zd          * (((unsigned)iz[1] < (unsigned)DD) ? 1.0f : 0.0f) };
        const unsigned ox[2] = { (unsigned)(min(max(ix[0], 0), HH - 1) * (WW * DD * CC)),
                                 (unsigned)(min(max(ix[1], 0), HH - 1) * (WW * DD * CC)) };
        const unsigned oy[2] = { (unsigned)(min(max(iy[0], 0), WW - 1) * (DD * CC)),
                                 (unsigned)(min(max(iy[1], 0), WW - 1) * (DD * CC)) };
        const unsigned oz[2] = { (unsigned)(min(max(iz[0], 0), DD - 1) * CC),
                                 (unsigned)(min(max(iz[1], 0), DD - 1) * CC) };

        #pragma unroll
        for (int i = 0; i < 8; ++i) {
            const int bx = (i >> 2) & 1, by = (i >> 1) & 1, bz = i & 1;
            off[v][i] = ox[bx] + oy[by] + oz[bz];
            wgt[v][i] = wxv[bx] * wyv[by] * wzv[bz];
        }
    }

    // ---- load phase: 16 pinned global_load_dwordx4, all in flight ----
    fx4 c[2][8];
    #pragma unroll
    for (int v = 0; v < 2; ++v)
        #pragma unroll
        for (int i = 0; i < 8; ++i) {
            const fx4* p = (const fx4*)(base + off[v][i]);
            asm volatile("global_load_dwordx4 %0, %1, off"
                         : "=v"(c[v][i]) : "v"(p) : "memory");
        }

    __builtin_amdgcn_sched_barrier(0);
    asm volatile("s_waitcnt vmcnt(8)" ::: "memory");   // voxel 0's 8 loads done (FIFO)
    __builtin_amdgcn_sched_barrier(0);

    fx4 acc0 = (fx4){0.f, 0.f, 0.f, 0.f};
    #pragma unroll
    for (int i = 0; i < 8; ++i) {
        acc0.x = fmaf(wgt[0][i], c[0][i].x, acc0.x);
        acc0.y = fmaf(wgt[0][i], c[0][i].y, acc0.y);
        acc0.z = fmaf(wgt[0][i], c[0][i].z, acc0.z);
        acc0.w = fmaf(wgt[0][i], c[0][i].w, acc0.w);
    }

    __builtin_amdgcn_sched_barrier(0);
    asm volatile("s_waitcnt vmcnt(0)" ::: "memory");   // voxel 1's loads done
    __builtin_amdgcn_sched_barrier(0);

    fx4 acc1 = (fx4){0.f, 0.f, 0.f, 0.f};
    #pragma unroll
    for (int i = 0; i < 8; ++i) {
        acc1.x = fmaf(wgt[1][i], c[1][i].x, acc1.x);
        acc1.y = fmaf(wgt[1][i], c[1][i].y, acc1.y);
        acc1.z = fmaf(wgt[1][i], c[1][i].z, acc1.z);
        acc1.w = fmaf(wgt[1][i], c[1][i].w, acc1.w);
    }

    const int vox0 = ((h0 * WW) + w) * DD + d;
    fx4* o0 = (fx4*)(out + (size_t)(bp * (HH * WW * DD) + vox0) * CC + half * 4);
    __builtin_nontemporal_store(acc0, o0);
    __builtin_nontemporal_store(acc1, (fx4*)((float*)o0 + WW * DD * CC));
}

extern "C" void kernel_launch(void* const* d_in, const int* in_sizes, int n_in,
                              void* d_out, int out_size, void* d_ws, size_t ws_size,
                              hipStream_t stream) {
    const float* fmap  = (const float*)d_in[0];
    const float* theta = (const float*)d_in[1];
    float* out = (float*)d_out;

    const int total_blocks = BB * PP * 128;   // 8192 blocks, 2 voxels/thread
    resample_kernel<<<dim3(total_blocks), dim3(256), 0, stream>>>(fmap, theta, out);
}